// Round 14
// baseline (238.960 us; speedup 1.0000x reference)
//
#include <hip/hip_runtime.h>
#include <math.h>

#define BB 2
#define NN 784
#define CC 384
#define DI 768
#define DS 64
#define DTR 24
#define ROWS (BB*NN)   // 1568
#define NC 16
#define LC 49          // NC*LC == NN

typedef __attribute__((ext_vector_type(8))) short bf16x8;
typedef __attribute__((ext_vector_type(4))) float f32x4;

static __device__ inline short f2bf(float f){
  unsigned u = __float_as_uint(f);
  unsigned r = (u + 0x7fffu + ((u>>16)&1u)) >> 16;
  return (short)r;
}
static __device__ inline float bf2f(short v){
  return __uint_as_float(((unsigned)(unsigned short)v)<<16);
}
static __device__ inline float rdlane(float v, int t){
  return __uint_as_float(__builtin_amdgcn_readlane(__float_as_uint(v), t));
}
template<int CTRL>
static __device__ inline float qp_add(float x){
  int t = __builtin_amdgcn_update_dpp(0, __float_as_int(x), CTRL, 0xf, 0xf, false);
  return x + __int_as_float(t);
}
#define QP_XOR1 0xB1   // quad_perm [1,0,3,2]
#define QP_XOR2 0x4E   // quad_perm [2,3,0,1]

// ---------------- 784-entry sincos table ----------------
__global__ void k_tab(float* __restrict__ ct, float* __restrict__ st){
  int i = blockIdx.x*256 + threadIdx.x;
  if (i < 784){
    float ang = 6.283185307179586f * (float)i / 784.f;
    float s, c; sincosf(ang, &s, &c);
    ct[i] = c; st[i] = s;
  }
}

// ---------------- LayerNorm (bf16 out): one wave per row of 384 ----------------
__global__ void k_ln(const float* __restrict__ x, const float* __restrict__ w,
                     const float* __restrict__ b, short* __restrict__ out, int rows){
  int row = blockIdx.x;
  if (row >= rows) return;
  int lane = threadIdx.x; // blockDim = 64
  const float* xr = x + (size_t)row*CC;
  float v[6]; float s = 0.f;
#pragma unroll
  for (int i=0;i<6;i++){ v[i] = xr[lane + 64*i]; s += v[i]; }
#pragma unroll
  for (int o=32;o;o>>=1) s += __shfl_xor(s,o);
  float mu = s * (1.f/CC);
  float vs = 0.f;
#pragma unroll
  for (int i=0;i<6;i++){ float d=v[i]-mu; vs += d*d; }
#pragma unroll
  for (int o=32;o;o>>=1) vs += __shfl_xor(vs,o);
  float rstd = rsqrtf(vs*(1.f/CC) + 1e-5f);
  short* orow = out + (size_t)row*CC;
#pragma unroll
  for (int i=0;i<6;i++){ int c = lane+64*i; orow[c] = f2bf((v[i]-mu)*rstd*w[c] + b[c]); }
}

// ---------------- LayerNorm transposed bf16 out: lnT[b][c][n] ----------------
__global__ void k_lnT(const float* __restrict__ x, const float* __restrict__ w,
                      const float* __restrict__ b, short* __restrict__ out){
  int row = blockIdx.x;      // b*784 + n
  if (row >= ROWS) return;
  int bb = row / NN, n = row % NN;
  int lane = threadIdx.x;
  const float* xr = x + (size_t)row*CC;
  float v[6]; float s = 0.f;
#pragma unroll
  for (int i=0;i<6;i++){ v[i] = xr[lane + 64*i]; s += v[i]; }
#pragma unroll
  for (int o=32;o;o>>=1) s += __shfl_xor(s,o);
  float mu = s * (1.f/CC);
  float vs = 0.f;
#pragma unroll
  for (int i=0;i<6;i++){ float d=v[i]-mu; vs += d*d; }
#pragma unroll
  for (int o=32;o;o>>=1) vs += __shfl_xor(vs,o);
  float rstd = rsqrtf(vs*(1.f/CC) + 1e-5f);
  short* ob = out + (size_t)bb*301056 + n;
#pragma unroll
  for (int i=0;i<6;i++){ int c = lane+64*i; ob[(size_t)c*NN] = f2bf((v[i]-mu)*rstd*w[c] + b[c]); }
}

// ---------------- bf16 MFMA GEMM, register double-buffered ----------------
// EPI 0: alpha*acc ; 1: alpha*acc + aux[row*ldaux+col] ; 2: relu(acc+aux[col]) ;
// 3: shrink(acc+aux[col],0.01) ; 4: atomicAdd(Y, alpha*acc) ; 5: softplus(acc+aux[col])
// BIG=0: 64x64 tile (waves 2x2, acc[2][2]) ; BIG=1: 128x64 tile (waves 4x1, acc[2][4])
template<int EPI, int ABF, int BBF, int SPLITK, int BIG>
__global__ __launch_bounds__(256) void k_mgemm(
    const void* __restrict__ Ap, int lda, long long Azs,
    const void* __restrict__ Bp, int ldb, long long Bzs,
    const float* __restrict__ aux, int ldaux, long long auxzs,
    float* __restrict__ Y, int ldo, long long Ozs,
    int M, int N, int K, float alpha)
{
  constexpr int BM = BIG ? 128 : 64;
  constexpr int NI = BIG ? 4 : 2;
  __shared__ __align__(16) short As[BM*32];
  __shared__ __align__(16) short Bs[64*32];
  int bz = blockIdx.z;
  int z  = bz / SPLITK, ks = bz % SPLITK;
  if (EPI == 1 || EPI == 2 || EPI == 3 || EPI == 5) aux += (size_t)z*auxzs;
  Y += (size_t)z*Ozs;
  int nk = (K + 31) >> 5;
  int per = (nk + SPLITK - 1) / SPLITK;
  int kbeg = ks*per*32;
  int kend = kbeg + per*32; if (kend > K) kend = K;
  if (kend <= kbeg) return;
  int ntile = (kend - kbeg + 31) >> 5;
  int m0 = blockIdx.y*BM, n0 = blockIdx.x*64;
  int t = threadIdx.x;
  int srow = t>>2, skg = t&3;
  int w = t>>6, lane = t&63;
  int wr = BIG ? (w*32) : ((w>>1)*32);
  int wc = BIG ? 0 : ((w&1)*32);
  int l15 = lane&15, lh = lane>>4;
  f32x4 acc[2][NI] = {};
  int sslot0 = skg ^ ((srow>>1)&3);
  int srow1 = srow + 64;
  int sslot1 = skg ^ ((srow1>>1)&3);
  int gmA0 = m0 + srow, gmA1 = m0 + srow1, gnB = n0 + srow;
  int gko = skg*8;

  bf16x8 vA0 = {}, vA1 = {}, vB = {};
  float4 fA00, fA01, fA10, fA11, fB0, fB1;

  auto LOAD = [&](int k0){
    int gk = k0 + gko;
    if (ABF){
      bf16x8 v = {};
      if (gmA0 < M && gk < K) v = *(const bf16x8*)((const short*)Ap + (size_t)z*Azs + (size_t)gmA0*lda + gk);
      vA0 = v;
      if (BIG){
        bf16x8 v1 = {};
        if (gmA1 < M && gk < K) v1 = *(const bf16x8*)((const short*)Ap + (size_t)z*Azs + (size_t)gmA1*lda + gk);
        vA1 = v1;
      }
    } else {
      fA00 = make_float4(0.f,0.f,0.f,0.f); fA01 = fA00;
      if (gmA0 < M && gk < K){
        const float* p = (const float*)Ap + (size_t)z*Azs + (size_t)gmA0*lda + gk;
        fA00 = *(const float4*)p; fA01 = *(const float4*)(p+4);
      }
      if (BIG){
        fA10 = make_float4(0.f,0.f,0.f,0.f); fA11 = fA10;
        if (gmA1 < M && gk < K){
          const float* p = (const float*)Ap + (size_t)z*Azs + (size_t)gmA1*lda + gk;
          fA10 = *(const float4*)p; fA11 = *(const float4*)(p+4);
        }
      }
    }
    if (BBF){
      bf16x8 v = {};
      if (gnB < N && gk < K) v = *(const bf16x8*)((const short*)Bp + (size_t)z*Bzs + (size_t)gnB*ldb + gk);
      vB = v;
    } else {
      fB0 = make_float4(0.f,0.f,0.f,0.f); fB1 = fB0;
      if (gnB < N && gk < K){
        const float* p = (const float*)Bp + (size_t)z*Bzs + (size_t)gnB*ldb + gk;
        fB0 = *(const float4*)p; fB1 = *(const float4*)(p+4);
      }
    }
  };
  auto STORE = [&](){
    if (ABF){
      *(bf16x8*)(As + srow*32 + sslot0*8) = vA0;
      if (BIG) *(bf16x8*)(As + srow1*32 + sslot1*8) = vA1;
    } else {
      union { short s[8]; bf16x8 v; } pk;
      pk.s[0]=f2bf(fA00.x); pk.s[1]=f2bf(fA00.y); pk.s[2]=f2bf(fA00.z); pk.s[3]=f2bf(fA00.w);
      pk.s[4]=f2bf(fA01.x); pk.s[5]=f2bf(fA01.y); pk.s[6]=f2bf(fA01.z); pk.s[7]=f2bf(fA01.w);
      *(bf16x8*)(As + srow*32 + sslot0*8) = pk.v;
      if (BIG){
        pk.s[0]=f2bf(fA10.x); pk.s[1]=f2bf(fA10.y); pk.s[2]=f2bf(fA10.z); pk.s[3]=f2bf(fA10.w);
        pk.s[4]=f2bf(fA11.x); pk.s[5]=f2bf(fA11.y); pk.s[6]=f2bf(fA11.z); pk.s[7]=f2bf(fA11.w);
        *(bf16x8*)(As + srow1*32 + sslot1*8) = pk.v;
      }
    }
    if (BBF) *(bf16x8*)(Bs + srow*32 + sslot0*8) = vB;
    else {
      union { short s[8]; bf16x8 v; } pk;
      pk.s[0]=f2bf(fB0.x); pk.s[1]=f2bf(fB0.y); pk.s[2]=f2bf(fB0.z); pk.s[3]=f2bf(fB0.w);
      pk.s[4]=f2bf(fB1.x); pk.s[5]=f2bf(fB1.y); pk.s[6]=f2bf(fB1.z); pk.s[7]=f2bf(fB1.w);
      *(bf16x8*)(Bs + srow*32 + sslot0*8) = pk.v;
    }
  };

  LOAD(kbeg);
  for (int ti=0; ti<ntile; ++ti){
    STORE();
    __syncthreads();
    if (ti+1 < ntile) LOAD(kbeg + (ti+1)*32);   // in-flight during MFMA
    bf16x8 af[2], bfr[NI];
#pragma unroll
    for (int mi=0; mi<2; mi++){
      int row = wr + mi*16 + l15;
      af[mi] = *(const bf16x8*)(As + row*32 + ((lh ^ ((row>>1)&3))<<3));
    }
#pragma unroll
    for (int ni=0; ni<NI; ni++){
      int col = wc + ni*16 + l15;
      bfr[ni] = *(const bf16x8*)(Bs + col*32 + ((lh ^ ((col>>1)&3))<<3));
    }
#pragma unroll
    for (int mi=0; mi<2; mi++)
#pragma unroll
      for (int ni=0; ni<NI; ni++)
        acc[mi][ni] = __builtin_amdgcn_mfma_f32_16x16x32_bf16(af[mi], bfr[ni], acc[mi][ni], 0, 0, 0);
    __syncthreads();
  }
  // ---- epilogue ----
#pragma unroll
  for (int mi=0; mi<2; mi++){
#pragma unroll
    for (int ni=0; ni<NI; ni++){
      int col = n0 + wc + ni*16 + l15;
      if (col >= N) continue;
#pragma unroll
      for (int j=0; j<4; j++){
        int row = m0 + wr + mi*16 + lh*4 + j;
        if (row >= M) continue;
        float v = acc[mi][ni][j];
        if (EPI == 0){ Y[(size_t)row*ldo + col] = v*alpha; }
        else if (EPI == 1){ Y[(size_t)row*ldo + col] = v*alpha + aux[(size_t)row*ldaux + col]; }
        else if (EPI == 2){ v += aux[col]; Y[(size_t)row*ldo + col] = fmaxf(v, 0.f); }
        else if (EPI == 3){ v += aux[col]; Y[(size_t)row*ldo + col] = copysignf(fmaxf(fabsf(v)-0.01f, 0.f), v); }
        else if (EPI == 5){ v += aux[col]; Y[(size_t)row*ldo + col] = (v>20.f)? v : log1pf(expf(v)); }
        else { atomicAdd(&Y[(size_t)row*ldo + col], v*alpha); }
      }
    }
  }
}

// ---------------- causal depthwise conv1d + silu (+ dbl zero-fill) ----------------
__global__ void k_conv(const float* __restrict__ xz, const float* __restrict__ cw,
                       const float* __restrict__ cb, float* __restrict__ xc,
                       float4* __restrict__ dbl4){
  int idx = blockIdx.x*256 + threadIdx.x;
  if (idx < 238336/4) dbl4[idx] = make_float4(0.f,0.f,0.f,0.f);
  if (idx >= ROWS*DI) return;
  int d = idx % DI;
  int r = idx / DI;
  int b = r / NN, l = r % NN;
  float acc = cb[d];
#pragma unroll
  for (int t=0;t<4;t++){
    int ls = l-3+t;
    if (ls>=0) acc += cw[d*4+t] * xz[((size_t)(b*NN+ls))*1536 + d];
  }
  xc[(size_t)r*DI + d] = acc / (1.f + expf(-acc)); // silu
}

// ---------------- chunked scan pass 1 (round-11 proven body) ----------------
__global__ __launch_bounds__(256) void k_scan1(
    const float* __restrict__ dbl, const float* __restrict__ dtb,
    const float* __restrict__ xc, const float* __restrict__ A_log,
    short* __restrict__ hpart, float* __restrict__ sdt)
{
  __shared__ float Sb[LC*64];
  int gx = blockIdx.x;                 // 32 * 192
  int bc = gx & 31, dgrp = gx >> 5;
  int b = bc >> 4, c = bc & 15;
  int wv = threadIdx.x >> 6, lane = threadIdx.x & 63;
  int d = dgrp*4 + wv;
  int t0 = c*LC;
  const float* dbr = dbl + ((size_t)(b*NN+t0))*152 + DTR;
  for (int i = threadIdx.x; i < LC*64; i += 256){
    int r = i >> 6, col = i & 63;
    Sb[i] = dbr[(size_t)r*152 + col];
  }
  __syncthreads();
  float A = -__expf(A_log[d*DS + lane]);
  const float* dtp = dtb + ((size_t)(b*NN+t0))*DI + d;
  const float* up  = xc  + ((size_t)(b*NN+t0))*DI + d;
  float dt0v = (lane<LC) ? dtp[(size_t)lane*DI] : 0.f;
  float u0v  = (lane<LC) ? up[(size_t)lane*DI]  : 0.f;
  float h = 0.f;
  for (int tb=0; tb<LC; tb+=7){
    float e[7], f[7];
#pragma unroll
    for (int j=0;j<7;j++){
      int t = tb+j;
      float dt = rdlane(dt0v, t);
      float u  = rdlane(u0v, t);
      e[j] = __expf(dt*A);
      f[j] = (dt*u)*Sb[t*64 + lane];
    }
#pragma unroll
    for (int j=0;j<7;j++) h = h*e[j] + f[j];
  }
  int bd = b*DI + d;
  hpart[((size_t)bd*NC + c)*DS + lane] = f2bf(h);
  float s = dt0v;
#pragma unroll
  for (int o=32;o;o>>=1) s += __shfl_xor(s,o);
  if (lane==0) sdt[bd*NC + c] = s;
}

// ---------------- chunked scan pass 2 ----------------
__global__ __launch_bounds__(256) void k_scan2(
    const float* __restrict__ sdt, const float* __restrict__ A_log,
    short* __restrict__ hpart)
{
  int wid = (blockIdx.x*256 + threadIdx.x) >> 6;
  int lane = threadIdx.x & 63;
  if (wid >= BB*DI) return;
  int d = wid % DI;
  float A = -__expf(A_log[d*DS + lane]);
  short* hp = hpart + (size_t)wid*NC*DS + lane;
  const float* sp = sdt + wid*NC;
  float part[NC], pA[NC];
#pragma unroll
  for (int c=0;c<NC;c++){ part[c] = bf2f(hp[(size_t)c*DS]); pA[c] = __expf(A*sp[c]); }
  float h = 0.f;
#pragma unroll
  for (int c=0;c<NC;c++){
    hp[(size_t)c*DS] = f2bf(h);   // hin for chunk c
    h = h*pA[c] + part[c];
  }
}

// ---------------- chunked scan pass 3 (round-11 proven body) ----------------
__global__ __launch_bounds__(256) void k_scan3(
    const float* __restrict__ dbl, const float* __restrict__ dtb,
    const float* __restrict__ xc, const float* __restrict__ xz,
    const float* __restrict__ A_log, const float* __restrict__ Dp,
    const short* __restrict__ hin, float* __restrict__ y)
{
  __shared__ float S[LC*128];          // interleaved {B,C}: S[t*128 + lane*2 + {0,1}]
  __shared__ float red[4][LC*17];
  int gx = blockIdx.x;
  int bc = gx & 31, dgrp = gx >> 5;
  int b = bc >> 4, c = bc & 15;
  int wv = threadIdx.x >> 6, lane = threadIdx.x & 63;
  int d = dgrp*4 + wv;
  int t0 = c*LC;
  const float* dbr = dbl + ((size_t)(b*NN+t0))*152 + DTR;
  for (int i = threadIdx.x; i < LC*128; i += 256){
    int r = i >> 7, col = i & 127;
    int ln = col & 63, which = col >> 6;
    S[r*128 + ln*2 + which] = dbr[(size_t)r*152 + col];
  }
  __syncthreads();
  float A = -__expf(A_log[d*DS + lane]);
  float Dv = Dp[d];
  const float* dtp = dtb + ((size_t)(b*NN+t0))*DI + d;
  const float* up  = xc  + ((size_t)(b*NN+t0))*DI + d;
  const float* zp  = xz  + ((size_t)(b*NN+t0))*1536 + DI + d;
  float* yp = y + ((size_t)(b*NN+t0))*DI + d;
  float dt0v = (lane<LC) ? dtp[(size_t)lane*DI]  : 0.f;
  float u0v  = (lane<LC) ? up[(size_t)lane*DI]   : 0.f;
  float z0v  = (lane<LC) ? zp[(size_t)lane*1536] : 0.f;
  int bd = b*DI + d;
  float h = bf2f(hin[((size_t)bd*NC + c)*DS + lane]);
  float* rw = red[wv];
  int g = lane>>2;
  bool gl = (lane&3)==0;
  for (int tb=0; tb<LC; tb+=7){
    float e[7], f[7], Cv[7];
#pragma unroll
    for (int j=0;j<7;j++){
      int t = tb+j;
      float2 bcv = *(const float2*)&S[t*128 + lane*2];
      float dt = rdlane(dt0v, t);
      float u  = rdlane(u0v, t);
      e[j]  = __expf(dt*A);
      f[j]  = (dt*u)*bcv.x;
      Cv[j] = bcv.y;
    }
#pragma unroll
    for (int j=0;j<7;j++){
      h = h*e[j] + f[j];
      float p = h*Cv[j];
      p = qp_add<QP_XOR1>(p);
      p = qp_add<QP_XOR2>(p);
      if (gl) rw[(tb+j)*17 + g] = p;
    }
  }
  if (lane < LC){
    const float* rr = rw + lane*17;
    float a0 = rr[0]+rr[4]+rr[8] +rr[12];
    float a1 = rr[1]+rr[5]+rr[9] +rr[13];
    float a2 = rr[2]+rr[6]+rr[10]+rr[14];
    float a3 = rr[3]+rr[7]+rr[11]+rr[15];
    float yv = (a0+a1)+(a2+a3) + u0v*Dv;      // lane == t
    float z = z0v;
    yp[(size_t)lane*DI] = yv * (z/(1.f+__expf(-z)));
  }
}

// ---------------- merged prep: twiddles (LUT gather) + EinFFT weights + Ybuf zero ----------------
__global__ void k_prep(short* __restrict__ Wcat, short* __restrict__ WT,
                       const float* __restrict__ ct, const float* __restrict__ st,
                       const float* __restrict__ cw1, const float* __restrict__ cb1,
                       const float* __restrict__ cw2, const float* __restrict__ cb2,
                       short* __restrict__ W1, short* __restrict__ W2,
                       float* __restrict__ b1, float* __restrict__ b2,
                       float4* __restrict__ Ybuf4){
  int idx = blockIdx.x*256+threadIdx.x;
  if (idx < 784*1568){
    int n = idx / 1568, f = idx % 1568;       // f fastest -> WT store coalesced
    int ff = (f<784)? f : f-784;
    int m = (ff*n) % 784;
    WT[(size_t)n*1568 + f] = f2bf((f<784)? ct[m] : -st[m]);
  } else if (idx < 2*784*1568){
    int r = idx - 784*1568;
    int f = r / 784, n = r % 784;             // n fastest -> Wcat store coalesced
    int ff = (f<784)? f : f-784;
    int m = (ff*n) % 784;
    Wcat[(size_t)f*784 + n] = f2bf((f<784)? ct[m] : -st[m]);
  }
  if (idx < 2*4*192*192){
    int l = idx / (4*192*192);
    int r = idx % (4*192*192);
    int d = r % 192; int j = (r/192) % 192; int bl = r/(192*192);
    int jj = j % 96, dd = d % 96;
    const float* cw = l ? cw2 : cw1;
    const float* w0 = cw + bl*9216;
    const float* w1 = cw + 4*9216 + bl*9216;
    float v;
    if (j < 96) v = (d < 96) ? w0[dd*96+jj] : -w1[dd*96+jj];
    else        v = (d < 96) ? w1[dd*96+jj] :  w0[dd*96+jj];
    (l ? W2 : W1)[r] = f2bf(v);
  }
  if (idx < 2*4*192){
    int l = idx / (4*192);
    int r = idx % (4*192);
    int j = r % 192; int bl = r/192;
    const float* cb = l ? cb2 : cb1;
    (l ? b2 : b1)[r] = (j<96) ? cb[bl*96 + j] : cb[384 + bl*96 + (j-96)];
  }
  if (idx < 301056) Ybuf4[idx] = make_float4(0.f,0.f,0.f,0.f);
}

// ---------------- forward length-4 DFT along nb -> tcat (bf16) ----------------
__global__ void k_cfft4(const float* __restrict__ Ybuf, short* __restrict__ tcat){
  int idx = blockIdx.x*256+threadIdx.x;
  if (idx >= BB*NN*96) return;
  int k = idx % 96; int r = idx / 96;
  int b = r / NN, f = r % NN;
  const float* fre = Ybuf + (size_t)b*602112 + (size_t)f*384;
  const float* fim = fre + 301056;
  float R0=fre[k], R1=fre[96+k], R2=fre[192+k], R3=fre[288+k];
  float I0=fim[k], I1=fim[96+k], I2=fim[192+k], I3=fim[288+k];
  short* tr = tcat + (size_t)r*768;
  tr[k]       = f2bf(R0+R1+R2+R3);  tr[96+k]    = f2bf(I0+I1+I2+I3);
  tr[192+k]   = f2bf(R0+I1-R2-I3);  tr[192+96+k]= f2bf(I0-R1-I2+R3);
  tr[384+k]   = f2bf(R0-R1+R2-R3);  tr[384+96+k]= f2bf(I0-I1+I2-I3);
  tr[576+k]   = f2bf(R0-I1-R2+I3);  tr[576+96+k]= f2bf(I0+R1-I2-R3);
}

// ---------------- inverse length-4 DFT -> YbufT[b][c][fcat] ----------------
__global__ void k_cifft4(const float* __restrict__ t2cat, float* __restrict__ YbufT){
  int idx = blockIdx.x*256+threadIdx.x;
  if (idx >= BB*NN*96) return;
  int f = idx % 784;
  int rest = idx / 784;
  int k = rest % 96;
  int b = rest / 96;
  const float* tr = t2cat + ((size_t)(b*NN+f))*768;
  float R0=tr[k],     I0=tr[96+k];
  float R1=tr[192+k], I1=tr[192+96+k];
  float R2=tr[384+k], I2=tr[384+96+k];
  float R3=tr[576+k], I3=tr[576+96+k];
  float* YT = YbufT + (size_t)b*602112;
  float gr[4], gi[4];
  gr[0]=R0+R1+R2+R3; gi[0]=I0+I1+I2+I3;
  gr[1]=R0-I1-R2+I3; gi[1]=I0+R1-I2-R3;
  gr[2]=R0-R1+R2-R3; gi[2]=I0-I1+I2-I3;
  gr[3]=R0+I1-R2-I3; gi[3]=I0-R1-I2+R3;
#pragma unroll
  for (int n=0;n<4;n++){
    int c = n*96 + k;
    YT[(size_t)c*1568 + f]       = gr[n];
    YT[(size_t)c*1568 + 784 + f] = gi[n];
  }
}

extern "C" void kernel_launch(void* const* d_in, const int* in_sizes, int n_in,
                              void* d_out, int out_size, void* d_ws, size_t ws_size,
                              hipStream_t stream){
  const float* x         = (const float*)d_in[0];
  const float* ln1_w     = (const float*)d_in[3];
  const float* ln1_b     = (const float*)d_in[4];
  const float* in_proj_w = (const float*)d_in[5];
  const float* conv_w    = (const float*)d_in[6];
  const float* conv_b    = (const float*)d_in[7];
  const float* x_proj_w  = (const float*)d_in[8];
  const float* dt_proj_w = (const float*)d_in[9];
  const float* dt_proj_b = (const float*)d_in[10];
  const float* A_log     = (const float*)d_in[11];
  const float* Dp        = (const float*)d_in[12];
  const float* out_proj_w= (const float*)d_in[13];
  const float* ln2_w     = (const float*)d_in[14];
  const float* ln2_b     = (const float*)d_in[15];
  const float* cw1       = (const float*)d_in[16];
  const float* cb1       = (const float*)d_in[17];
  const float* cw2       = (const float*)d_in[18];
  const float* cb2       = (const float*)d_in[19];

  float* ws = (float*)d_ws;
  // ---- phase A (mamba) ----
  short* lnb  = (short*)ws;          // bf16 ln1 out: floats [0, 301056)
  float* xz   = ws + 602112;         // [602112, 3010560)
  float* xc   = ws + 3010560;        // [3010560, 4214784)
  float* dbl  = ws + 4214784;        // [4214784, 4453120)
  float* dtb  = ws + 4453120;        // [4453120, 5657344)
  float* yb   = ws + 5657344;        // [5657344, 6861568)
  float* x1   = ws + 6861568;        // [6861568, 7463680)  persists to end
  short* hpart= (short*)(ws + 7463680); // bf16: floats [7463680, 8250112)
  float* sdt  = ws + 8250112;        // [8250112, 8274688)
  float* ctab = ws + 8274688;        // [8274688, 8275472)
  float* stab = ws + 8275472;        // [8275472, 8276256)
  // ---- phase B (einfft), overlaid on regions dead by launch order ----
  short* Wcat = (short*)(ws + 602112);   // floats [602112, 1216768)
  short* lnT  = (short*)(ws + 1831424);  // floats [1831424, 2132480)
  float* Ybuf = ws + 2433536;            // [2433536, 3637760)
  short* WT   = (short*)(ws + 4453120);  // floats [4453120, 5067776) over dead dtb
  short* tcat = (short*)(ws + 602112);   // floats [602112, 1204224) over dead Wcat
  float* o1cat= ws + 1806336;            // [1806336, 3010560)
  float* t2cat= ws + 3010560;            // [3010560, 4214784)
  float* YbufT= ws + 602112;             // [602112, 1806336)  over dead tcat
  short* W1c  = (short*)(ws + 7463680);  // floats [7463680, 7537408) over dead hpart
  short* W2c  = (short*)(ws + 7537408);  // floats [7537408, 7611136)
  float* b1c  = ws + 7611136;            // [7611136, 7611904)
  float* b2c  = ws + 7611904;            // [7611904, 7612672)

  // ---- independent tiny prep ----
  k_tab<<<4,256,0,stream>>>(ctab, stab);
  hipMemcpyAsync(x1, x, (size_t)602112*4, hipMemcpyDeviceToDevice, stream);

  // ---- mamba path ----
  k_ln<<<ROWS,64,0,stream>>>(x, ln1_w, ln1_b, lnb, ROWS);
  k_mgemm<0,1,0,1,1><<<dim3(24,13,1),256,0,stream>>>(lnb,384,0, in_proj_w,384,0, nullptr,0,0,
                                                     xz,1536,0, ROWS,1536,384, 1.f);
  k_conv<<<(ROWS*DI+255)/256,256,0,stream>>>(xz,conv_w,conv_b,xc,(float4*)dbl);
  k_mgemm<4,0,0,8,1><<<dim3(3,13,8),256,0,stream>>>(xc,768,0, x_proj_w,768,0, nullptr,0,0,
                                                    dbl,152,0, ROWS,152,768, 1.f);
  // dt_proj: MFMA, single zero-padded k-tile (K=24), softplus+bias epilogue
  k_mgemm<5,0,0,1,0><<<dim3(12,25,1),256,0,stream>>>(dbl,152,0, dt_proj_w,24,0, dt_proj_b,0,0,
                                                     dtb,768,0, ROWS,768,24, 1.f);
  k_scan1<<<32*192,256,0,stream>>>(dbl,dtb,xc,A_log,hpart,sdt);
  k_scan2<<<(BB*DI)/4,256,0,stream>>>(sdt,A_log,hpart);
  k_scan3<<<32*192,256,0,stream>>>(dbl,dtb,xc,xz,A_log,Dp,hpart,yb);
  k_mgemm<4,0,0,4,1><<<dim3(6,13,4),256,0,stream>>>(yb,768,0, out_proj_w,768,0, nullptr,0,0,
                                                    x1,384,0, ROWS,384,768, 1.f);

  // ---- einfft path (prep after mamba: overlaid regions now dead) ----
  k_prep<<<(2*784*1568+255)/256,256,0,stream>>>(Wcat,WT,ctab,stab,cw1,cb1,cw2,cb2,W1c,W2c,b1c,b2c,(float4*)Ybuf);
  k_lnT<<<ROWS,64,0,stream>>>(x1, ln2_w, ln2_b, lnT);
  // forward DFT-784: split-K 4, atomic into zeroed Ybuf (A=Wcat bf16, B=lnT bf16)
  k_mgemm<4,1,1,4,1><<<dim3(6,13,8),256,0,stream>>>(Wcat,784,0, lnT,784,301056, nullptr,0,0,
                                                    Ybuf,384,602112, 1568,384,784, 1.f/56.f);
  // forward DFT-4 along nb -> tcat (bf16)
  k_cfft4<<<(BB*NN*96+255)/256,256,0,stream>>>(Ybuf,tcat);
  // EinFFT layer 1 (relu), A=tcat bf16
  k_mgemm<2,1,1,1,0><<<dim3(3,25,4),256,0,stream>>>(tcat,768,192, W1c,192,36864, b1c,0,192,
                                                    o1cat,768,192, ROWS,192,192, 1.f);
  // EinFFT layer 2 (soft shrink)
  k_mgemm<3,0,1,1,0><<<dim3(3,25,4),256,0,stream>>>(o1cat,768,192, W2c,192,36864, b2c,0,192,
                                                    t2cat,768,192, ROWS,192,192, 1.f);
  // inverse DFT-4 -> YbufT[b][c][fcat]
  k_cifft4<<<(BB*NN*96+255)/256,256,0,stream>>>(t2cat,YbufT);
  hipMemcpyAsync(d_out, x1, (size_t)602112*4, hipMemcpyDeviceToDevice, stream);
  // inverse DFT-784: split-K 7, atomic into d_out (A=WT bf16)
  k_mgemm<4,1,0,7,1><<<dim3(6,7,14),256,0,stream>>>(WT,1568,0, YbufT,1568,602112, nullptr,0,0,
                                                    (float*)d_out,384,301056, 784,384,1568, 1.f/56.f);
}

// Round 15
// 235.042 us; speedup vs baseline: 1.0167x; 1.0167x over previous
//
#include <hip/hip_runtime.h>
#include <math.h>

#define BB 2
#define NN 784
#define CC 384
#define DI 768
#define DS 64
#define DTR 24
#define ROWS (BB*NN)   // 1568
#define NC 16
#define LC 49          // NC*LC == NN

typedef __attribute__((ext_vector_type(8))) short bf16x8;
typedef __attribute__((ext_vector_type(4))) float f32x4;

static __device__ inline short f2bf(float f){
  unsigned u = __float_as_uint(f);
  unsigned r = (u + 0x7fffu + ((u>>16)&1u)) >> 16;
  return (short)r;
}
static __device__ inline float bf2f(short v){
  return __uint_as_float(((unsigned)(unsigned short)v)<<16);
}
static __device__ inline float rdlane(float v, int t){
  return __uint_as_float(__builtin_amdgcn_readlane(__float_as_uint(v), t));
}
template<int CTRL>
static __device__ inline float qp_add(float x){
  int t = __builtin_amdgcn_update_dpp(0, __float_as_int(x), CTRL, 0xf, 0xf, false);
  return x + __int_as_float(t);
}
#define QP_XOR1 0xB1   // quad_perm [1,0,3,2]
#define QP_XOR2 0x4E   // quad_perm [2,3,0,1]

// ---------------- 784-entry sincos table ----------------
__global__ void k_tab(float* __restrict__ ct, float* __restrict__ st){
  int i = blockIdx.x*256 + threadIdx.x;
  if (i < 784){
    float ang = 6.283185307179586f * (float)i / 784.f;
    float s, c; sincosf(ang, &s, &c);
    ct[i] = c; st[i] = s;
  }
}

// ---------------- LayerNorm (bf16 out): one wave per row of 384 ----------------
__global__ void k_ln(const float* __restrict__ x, const float* __restrict__ w,
                     const float* __restrict__ b, short* __restrict__ out, int rows){
  int row = blockIdx.x;
  if (row >= rows) return;
  int lane = threadIdx.x; // blockDim = 64
  const float* xr = x + (size_t)row*CC;
  float v[6]; float s = 0.f;
#pragma unroll
  for (int i=0;i<6;i++){ v[i] = xr[lane + 64*i]; s += v[i]; }
#pragma unroll
  for (int o=32;o;o>>=1) s += __shfl_xor(s,o);
  float mu = s * (1.f/CC);
  float vs = 0.f;
#pragma unroll
  for (int i=0;i<6;i++){ float d=v[i]-mu; vs += d*d; }
#pragma unroll
  for (int o=32;o;o>>=1) vs += __shfl_xor(vs,o);
  float rstd = rsqrtf(vs*(1.f/CC) + 1e-5f);
  short* orow = out + (size_t)row*CC;
#pragma unroll
  for (int i=0;i<6;i++){ int c = lane+64*i; orow[c] = f2bf((v[i]-mu)*rstd*w[c] + b[c]); }
}

// ---------------- LayerNorm transposed bf16 out: lnT[b][c][n] ----------------
__global__ void k_lnT(const float* __restrict__ x, const float* __restrict__ w,
                      const float* __restrict__ b, short* __restrict__ out){
  int row = blockIdx.x;      // b*784 + n
  if (row >= ROWS) return;
  int bb = row / NN, n = row % NN;
  int lane = threadIdx.x;
  const float* xr = x + (size_t)row*CC;
  float v[6]; float s = 0.f;
#pragma unroll
  for (int i=0;i<6;i++){ v[i] = xr[lane + 64*i]; s += v[i]; }
#pragma unroll
  for (int o=32;o;o>>=1) s += __shfl_xor(s,o);
  float mu = s * (1.f/CC);
  float vs = 0.f;
#pragma unroll
  for (int i=0;i<6;i++){ float d=v[i]-mu; vs += d*d; }
#pragma unroll
  for (int o=32;o;o>>=1) vs += __shfl_xor(vs,o);
  float rstd = rsqrtf(vs*(1.f/CC) + 1e-5f);
  short* ob = out + (size_t)bb*301056 + n;
#pragma unroll
  for (int i=0;i<6;i++){ int c = lane+64*i; ob[(size_t)c*NN] = f2bf((v[i]-mu)*rstd*w[c] + b[c]); }
}

// ---------------- bf16 MFMA GEMM, register double-buffered (64x64 tile) ----------------
// EPI 0: alpha*acc ; 1: alpha*acc + aux[row*ldaux+col] ; 2: relu(acc+aux[col]) ;
// 3: shrink(acc+aux[col],0.01) ; 4: atomicAdd(Y, alpha*acc) ; 5: softplus(acc+aux[col])
template<int EPI, int ABF, int BBF, int SPLITK>
__global__ __launch_bounds__(256) void k_mgemm(
    const void* __restrict__ Ap, int lda, long long Azs,
    const void* __restrict__ Bp, int ldb, long long Bzs,
    const float* __restrict__ aux, int ldaux, long long auxzs,
    float* __restrict__ Y, int ldo, long long Ozs,
    int M, int N, int K, float alpha)
{
  __shared__ __align__(16) short As[64*32];
  __shared__ __align__(16) short Bs[64*32];
  int bz = blockIdx.z;
  int z  = bz / SPLITK, ks = bz % SPLITK;
  if (EPI == 1 || EPI == 2 || EPI == 3 || EPI == 5) aux += (size_t)z*auxzs;
  Y += (size_t)z*Ozs;
  int nk = (K + 31) >> 5;
  int per = (nk + SPLITK - 1) / SPLITK;
  int kbeg = ks*per*32;
  int kend = kbeg + per*32; if (kend > K) kend = K;
  if (kend <= kbeg) return;
  int ntile = (kend - kbeg + 31) >> 5;
  int m0 = blockIdx.y*64, n0 = blockIdx.x*64;
  int t = threadIdx.x;
  int srow = t>>2, skg = t&3;
  int w = t>>6, lane = t&63;
  int wr = (w>>1)*32, wc = (w&1)*32;
  int l15 = lane&15, lh = lane>>4;
  f32x4 acc[2][2] = {};
  int sslot = skg ^ ((srow>>1)&3);
  int gmA = m0 + srow, gnB = n0 + srow;
  int gko = skg*8;

  bf16x8 vA = {}, vB = {};
  float4 fA0, fA1, fB0, fB1;

  auto LOAD = [&](int k0){
    int gk = k0 + gko;
    if (ABF){
      bf16x8 v = {};
      if (gmA < M && gk < K) v = *(const bf16x8*)((const short*)Ap + (size_t)z*Azs + (size_t)gmA*lda + gk);
      vA = v;
    } else {
      fA0 = make_float4(0.f,0.f,0.f,0.f); fA1 = fA0;
      if (gmA < M && gk < K){
        const float* p = (const float*)Ap + (size_t)z*Azs + (size_t)gmA*lda + gk;
        fA0 = *(const float4*)p; fA1 = *(const float4*)(p+4);
      }
    }
    if (BBF){
      bf16x8 v = {};
      if (gnB < N && gk < K) v = *(const bf16x8*)((const short*)Bp + (size_t)z*Bzs + (size_t)gnB*ldb + gk);
      vB = v;
    } else {
      fB0 = make_float4(0.f,0.f,0.f,0.f); fB1 = fB0;
      if (gnB < N && gk < K){
        const float* p = (const float*)Bp + (size_t)z*Bzs + (size_t)gnB*ldb + gk;
        fB0 = *(const float4*)p; fB1 = *(const float4*)(p+4);
      }
    }
  };
  auto STORE = [&](){
    if (ABF) *(bf16x8*)(As + srow*32 + sslot*8) = vA;
    else {
      union { short s[8]; bf16x8 v; } pk;
      pk.s[0]=f2bf(fA0.x); pk.s[1]=f2bf(fA0.y); pk.s[2]=f2bf(fA0.z); pk.s[3]=f2bf(fA0.w);
      pk.s[4]=f2bf(fA1.x); pk.s[5]=f2bf(fA1.y); pk.s[6]=f2bf(fA1.z); pk.s[7]=f2bf(fA1.w);
      *(bf16x8*)(As + srow*32 + sslot*8) = pk.v;
    }
    if (BBF) *(bf16x8*)(Bs + srow*32 + sslot*8) = vB;
    else {
      union { short s[8]; bf16x8 v; } pk;
      pk.s[0]=f2bf(fB0.x); pk.s[1]=f2bf(fB0.y); pk.s[2]=f2bf(fB0.z); pk.s[3]=f2bf(fB0.w);
      pk.s[4]=f2bf(fB1.x); pk.s[5]=f2bf(fB1.y); pk.s[6]=f2bf(fB1.z); pk.s[7]=f2bf(fB1.w);
      *(bf16x8*)(Bs + srow*32 + sslot*8) = pk.v;
    }
  };

  LOAD(kbeg);
  for (int ti=0; ti<ntile; ++ti){
    STORE();
    __syncthreads();
    if (ti+1 < ntile) LOAD(kbeg + (ti+1)*32);   // in-flight during MFMA
    bf16x8 af[2], bfr[2];
#pragma unroll
    for (int mi=0; mi<2; mi++){
      int row = wr + mi*16 + l15;
      af[mi] = *(const bf16x8*)(As + row*32 + ((lh ^ ((row>>1)&3))<<3));
    }
#pragma unroll
    for (int ni=0; ni<2; ni++){
      int col = wc + ni*16 + l15;
      bfr[ni] = *(const bf16x8*)(Bs + col*32 + ((lh ^ ((col>>1)&3))<<3));
    }
#pragma unroll
    for (int mi=0; mi<2; mi++)
#pragma unroll
      for (int ni=0; ni<2; ni++)
        acc[mi][ni] = __builtin_amdgcn_mfma_f32_16x16x32_bf16(af[mi], bfr[ni], acc[mi][ni], 0, 0, 0);
    __syncthreads();
  }
  // ---- epilogue ----
#pragma unroll
  for (int mi=0; mi<2; mi++){
#pragma unroll
    for (int ni=0; ni<2; ni++){
      int col = n0 + wc + ni*16 + l15;
      if (col >= N) continue;
#pragma unroll
      for (int j=0; j<4; j++){
        int row = m0 + wr + mi*16 + lh*4 + j;
        if (row >= M) continue;
        float v = acc[mi][ni][j];
        if (EPI == 0){ Y[(size_t)row*ldo + col] = v*alpha; }
        else if (EPI == 1){ Y[(size_t)row*ldo + col] = v*alpha + aux[(size_t)row*ldaux + col]; }
        else if (EPI == 2){ v += aux[col]; Y[(size_t)row*ldo + col] = fmaxf(v, 0.f); }
        else if (EPI == 3){ v += aux[col]; Y[(size_t)row*ldo + col] = copysignf(fmaxf(fabsf(v)-0.01f, 0.f), v); }
        else if (EPI == 5){ v += aux[col]; Y[(size_t)row*ldo + col] = (v>20.f)? v : log1pf(expf(v)); }
        else { atomicAdd(&Y[(size_t)row*ldo + col], v*alpha); }
      }
    }
  }
}

// ---------------- causal depthwise conv1d + silu (+ dbl zero-fill) ----------------
__global__ void k_conv(const float* __restrict__ xz, const float* __restrict__ cw,
                       const float* __restrict__ cb, float* __restrict__ xc,
                       float4* __restrict__ dbl4){
  int idx = blockIdx.x*256 + threadIdx.x;
  if (idx < 238336/4) dbl4[idx] = make_float4(0.f,0.f,0.f,0.f);
  if (idx >= ROWS*DI) return;
  int d = idx % DI;
  int r = idx / DI;
  int b = r / NN, l = r % NN;
  float acc = cb[d];
#pragma unroll
  for (int t=0;t<4;t++){
    int ls = l-3+t;
    if (ls>=0) acc += cw[d*4+t] * xz[((size_t)(b*NN+ls))*1536 + d];
  }
  xc[(size_t)r*DI + d] = acc / (1.f + expf(-acc)); // silu
}

// ---------------- chunked scan pass 1 (round-11 proven body) ----------------
__global__ __launch_bounds__(256) void k_scan1(
    const float* __restrict__ dbl, const float* __restrict__ dtb,
    const float* __restrict__ xc, const float* __restrict__ A_log,
    short* __restrict__ hpart, float* __restrict__ sdt)
{
  __shared__ float Sb[LC*64];
  int gx = blockIdx.x;                 // 32 * 192
  int bc = gx & 31, dgrp = gx >> 5;
  int b = bc >> 4, c = bc & 15;
  int wv = threadIdx.x >> 6, lane = threadIdx.x & 63;
  int d = dgrp*4 + wv;
  int t0 = c*LC;
  const float* dbr = dbl + ((size_t)(b*NN+t0))*152 + DTR;
  for (int i = threadIdx.x; i < LC*64; i += 256){
    int r = i >> 6, col = i & 63;
    Sb[i] = dbr[(size_t)r*152 + col];
  }
  __syncthreads();
  float A = -__expf(A_log[d*DS + lane]);
  const float* dtp = dtb + ((size_t)(b*NN+t0))*DI + d;
  const float* up  = xc  + ((size_t)(b*NN+t0))*DI + d;
  float dt0v = (lane<LC) ? dtp[(size_t)lane*DI] : 0.f;
  float u0v  = (lane<LC) ? up[(size_t)lane*DI]  : 0.f;
  float h = 0.f;
  for (int tb=0; tb<LC; tb+=7){
    float e[7], f[7];
#pragma unroll
    for (int j=0;j<7;j++){
      int t = tb+j;
      float dt = rdlane(dt0v, t);
      float u  = rdlane(u0v, t);
      e[j] = __expf(dt*A);
      f[j] = (dt*u)*Sb[t*64 + lane];
    }
#pragma unroll
    for (int j=0;j<7;j++) h = h*e[j] + f[j];
  }
  int bd = b*DI + d;
  hpart[((size_t)bd*NC + c)*DS + lane] = f2bf(h);
  float s = dt0v;
#pragma unroll
  for (int o=32;o;o>>=1) s += __shfl_xor(s,o);
  if (lane==0) sdt[bd*NC + c] = s;
}

// ---------------- chunked scan pass 2 ----------------
__global__ __launch_bounds__(256) void k_scan2(
    const float* __restrict__ sdt, const float* __restrict__ A_log,
    short* __restrict__ hpart)
{
  int wid = (blockIdx.x*256 + threadIdx.x) >> 6;
  int lane = threadIdx.x & 63;
  if (wid >= BB*DI) return;
  int d = wid % DI;
  float A = -__expf(A_log[d*DS + lane]);
  short* hp = hpart + (size_t)wid*NC*DS + lane;
  const float* sp = sdt + wid*NC;
  float part[NC], pA[NC];
#pragma unroll
  for (int c=0;c<NC;c++){ part[c] = bf2f(hp[(size_t)c*DS]); pA[c] = __expf(A*sp[c]); }
  float h = 0.f;
#pragma unroll
  for (int c=0;c<NC;c++){
    hp[(size_t)c*DS] = f2bf(h);   // hin for chunk c
    h = h*pA[c] + part[c];
  }
}

// ---------------- chunked scan pass 3 (round-11 proven body) ----------------
__global__ __launch_bounds__(256) void k_scan3(
    const float* __restrict__ dbl, const float* __restrict__ dtb,
    const float* __restrict__ xc, const float* __restrict__ xz,
    const float* __restrict__ A_log, const float* __restrict__ Dp,
    const short* __restrict__ hin, float* __restrict__ y)
{
  __shared__ float S[LC*128];          // interleaved {B,C}: S[t*128 + lane*2 + {0,1}]
  __shared__ float red[4][LC*17];
  int gx = blockIdx.x;
  int bc = gx & 31, dgrp = gx >> 5;
  int b = bc >> 4, c = bc & 15;
  int wv = threadIdx.x >> 6, lane = threadIdx.x & 63;
  int d = dgrp*4 + wv;
  int t0 = c*LC;
  const float* dbr = dbl + ((size_t)(b*NN+t0))*152 + DTR;
  for (int i = threadIdx.x; i < LC*128; i += 256){
    int r = i >> 7, col = i & 127;
    int ln = col & 63, which = col >> 6;
    S[r*128 + ln*2 + which] = dbr[(size_t)r*152 + col];
  }
  __syncthreads();
  float A = -__expf(A_log[d*DS + lane]);
  float Dv = Dp[d];
  const float* dtp = dtb + ((size_t)(b*NN+t0))*DI + d;
  const float* up  = xc  + ((size_t)(b*NN+t0))*DI + d;
  const float* zp  = xz  + ((size_t)(b*NN+t0))*1536 + DI + d;
  float* yp = y + ((size_t)(b*NN+t0))*DI + d;
  float dt0v = (lane<LC) ? dtp[(size_t)lane*DI]  : 0.f;
  float u0v  = (lane<LC) ? up[(size_t)lane*DI]   : 0.f;
  float z0v  = (lane<LC) ? zp[(size_t)lane*1536] : 0.f;
  int bd = b*DI + d;
  float h = bf2f(hin[((size_t)bd*NC + c)*DS + lane]);
  float* rw = red[wv];
  int g = lane>>2;
  bool gl = (lane&3)==0;
  for (int tb=0; tb<LC; tb+=7){
    float e[7], f[7], Cv[7];
#pragma unroll
    for (int j=0;j<7;j++){
      int t = tb+j;
      float2 bcv = *(const float2*)&S[t*128 + lane*2];
      float dt = rdlane(dt0v, t);
      float u  = rdlane(u0v, t);
      e[j]  = __expf(dt*A);
      f[j]  = (dt*u)*bcv.x;
      Cv[j] = bcv.y;
    }
#pragma unroll
    for (int j=0;j<7;j++){
      h = h*e[j] + f[j];
      float p = h*Cv[j];
      p = qp_add<QP_XOR1>(p);
      p = qp_add<QP_XOR2>(p);
      if (gl) rw[(tb+j)*17 + g] = p;
    }
  }
  if (lane < LC){
    const float* rr = rw + lane*17;
    float a0 = rr[0]+rr[4]+rr[8] +rr[12];
    float a1 = rr[1]+rr[5]+rr[9] +rr[13];
    float a2 = rr[2]+rr[6]+rr[10]+rr[14];
    float a3 = rr[3]+rr[7]+rr[11]+rr[15];
    float yv = (a0+a1)+(a2+a3) + u0v*Dv;      // lane == t
    float z = z0v;
    yp[(size_t)lane*DI] = yv * (z/(1.f+__expf(-z)));
  }
}

// ---------------- merged prep: twiddles (LUT gather) + EinFFT weights + Ybuf zero ----------------
__global__ void k_prep(short* __restrict__ Wcat, short* __restrict__ WT,
                       const float* __restrict__ ct, const float* __restrict__ st,
                       const float* __restrict__ cw1, const float* __restrict__ cb1,
                       const float* __restrict__ cw2, const float* __restrict__ cb2,
                       short* __restrict__ W1, short* __restrict__ W2,
                       float* __restrict__ b1, float* __restrict__ b2,
                       float4* __restrict__ Ybuf4){
  int idx = blockIdx.x*256+threadIdx.x;
  if (idx < 784*1568){
    int n = idx / 1568, f = idx % 1568;       // f fastest -> WT store coalesced
    int ff = (f<784)? f : f-784;
    int m = (ff*n) % 784;
    WT[(size_t)n*1568 + f] = f2bf((f<784)? ct[m] : -st[m]);
  } else if (idx < 2*784*1568){
    int r = idx - 784*1568;
    int f = r / 784, n = r % 784;             // n fastest -> Wcat store coalesced
    int ff = (f<784)? f : f-784;
    int m = (ff*n) % 784;
    Wcat[(size_t)f*784 + n] = f2bf((f<784)? ct[m] : -st[m]);
  }
  if (idx < 2*4*192*192){
    int l = idx / (4*192*192);
    int r = idx % (4*192*192);
    int d = r % 192; int j = (r/192) % 192; int bl = r/(192*192);
    int jj = j % 96, dd = d % 96;
    const float* cw = l ? cw2 : cw1;
    const float* w0 = cw + bl*9216;
    const float* w1 = cw + 4*9216 + bl*9216;
    float v;
    if (j < 96) v = (d < 96) ? w0[dd*96+jj] : -w1[dd*96+jj];
    else        v = (d < 96) ? w1[dd*96+jj] :  w0[dd*96+jj];
    (l ? W2 : W1)[r] = f2bf(v);
  }
  if (idx < 2*4*192){
    int l = idx / (4*192);
    int r = idx % (4*192);
    int j = r % 192; int bl = r/192;
    const float* cb = l ? cb2 : cb1;
    (l ? b2 : b1)[r] = (j<96) ? cb[bl*96 + j] : cb[384 + bl*96 + (j-96)];
  }
  if (idx < 301056) Ybuf4[idx] = make_float4(0.f,0.f,0.f,0.f);
}

// ---------------- forward length-4 DFT along nb -> tcat (bf16) ----------------
__global__ void k_cfft4(const float* __restrict__ Ybuf, short* __restrict__ tcat){
  int idx = blockIdx.x*256+threadIdx.x;
  if (idx >= BB*NN*96) return;
  int k = idx % 96; int r = idx / 96;
  int b = r / NN, f = r % NN;
  const float* fre = Ybuf + (size_t)b*602112 + (size_t)f*384;
  const float* fim = fre + 301056;
  float R0=fre[k], R1=fre[96+k], R2=fre[192+k], R3=fre[288+k];
  float I0=fim[k], I1=fim[96+k], I2=fim[192+k], I3=fim[288+k];
  short* tr = tcat + (size_t)r*768;
  tr[k]       = f2bf(R0+R1+R2+R3);  tr[96+k]    = f2bf(I0+I1+I2+I3);
  tr[192+k]   = f2bf(R0+I1-R2-I3);  tr[192+96+k]= f2bf(I0-R1-I2+R3);
  tr[384+k]   = f2bf(R0-R1+R2-R3);  tr[384+96+k]= f2bf(I0-I1+I2-I3);
  tr[576+k]   = f2bf(R0-I1-R2+I3);  tr[576+96+k]= f2bf(I0+R1-I2-R3);
}

// ---------------- inverse length-4 DFT -> YbufT[b][c][fcat] (bf16 out) ----------------
__global__ void k_cifft4(const float* __restrict__ t2cat, short* __restrict__ YbufT){
  int idx = blockIdx.x*256+threadIdx.x;
  if (idx >= BB*NN*96) return;
  int f = idx % 784;
  int rest = idx / 784;
  int k = rest % 96;
  int b = rest / 96;
  const float* tr = t2cat + ((size_t)(b*NN+f))*768;
  float R0=tr[k],     I0=tr[96+k];
  float R1=tr[192+k], I1=tr[192+96+k];
  float R2=tr[384+k], I2=tr[384+96+k];
  float R3=tr[576+k], I3=tr[576+96+k];
  short* YT = YbufT + (size_t)b*602112;
  float gr[4], gi[4];
  gr[0]=R0+R1+R2+R3; gi[0]=I0+I1+I2+I3;
  gr[1]=R0-I1-R2+I3; gi[1]=I0+R1-I2-R3;
  gr[2]=R0-R1+R2-R3; gi[2]=I0-I1+I2-I3;
  gr[3]=R0+I1-R2-I3; gi[3]=I0-R1-I2+R3;
#pragma unroll
  for (int n=0;n<4;n++){
    int c = n*96 + k;
    YT[(size_t)c*1568 + f]       = f2bf(gr[n]);
    YT[(size_t)c*1568 + 784 + f] = f2bf(gi[n]);
  }
}

extern "C" void kernel_launch(void* const* d_in, const int* in_sizes, int n_in,
                              void* d_out, int out_size, void* d_ws, size_t ws_size,
                              hipStream_t stream){
  const float* x         = (const float*)d_in[0];
  const float* ln1_w     = (const float*)d_in[3];
  const float* ln1_b     = (const float*)d_in[4];
  const float* in_proj_w = (const float*)d_in[5];
  const float* conv_w    = (const float*)d_in[6];
  const float* conv_b    = (const float*)d_in[7];
  const float* x_proj_w  = (const float*)d_in[8];
  const float* dt_proj_w = (const float*)d_in[9];
  const float* dt_proj_b = (const float*)d_in[10];
  const float* A_log     = (const float*)d_in[11];
  const float* Dp        = (const float*)d_in[12];
  const float* out_proj_w= (const float*)d_in[13];
  const float* ln2_w     = (const float*)d_in[14];
  const float* ln2_b     = (const float*)d_in[15];
  const float* cw1       = (const float*)d_in[16];
  const float* cb1       = (const float*)d_in[17];
  const float* cw2       = (const float*)d_in[18];
  const float* cb2       = (const float*)d_in[19];

  float* ws = (float*)d_ws;
  // ---- phase A (mamba) ----
  short* lnb  = (short*)ws;          // bf16 ln1 out: floats [0, 301056)
  float* xz   = ws + 602112;         // [602112, 3010560)
  float* xc   = ws + 3010560;        // [3010560, 4214784)
  float* dbl  = ws + 4214784;        // [4214784, 4453120)
  float* dtb  = ws + 4453120;        // [4453120, 5657344)
  float* yb   = ws + 5657344;        // [5657344, 6861568)
  float* x1   = ws + 6861568;        // [6861568, 7463680)  persists to end
  short* hpart= (short*)(ws + 7463680); // bf16: floats [7463680, 8250112)
  float* sdt  = ws + 8250112;        // [8250112, 8274688)
  float* ctab = ws + 8274688;        // [8274688, 8275472)
  float* stab = ws + 8275472;        // [8275472, 8276256)
  // ---- phase B (einfft), overlaid on regions dead by launch order ----
  short* Wcat = (short*)(ws + 602112);   // floats [602112, 1216768)
  short* lnT  = (short*)(ws + 1831424);  // floats [1831424, 2132480)
  float* Ybuf = ws + 2433536;            // [2433536, 3637760)
  short* WT   = (short*)(ws + 4453120);  // floats [4453120, 5067776) over dead dtb
  short* tcat = (short*)(ws + 602112);   // floats [602112, 1204224) over dead Wcat
  float* o1cat= ws + 1806336;            // [1806336, 3010560)
  float* t2cat= ws + 3010560;            // [3010560, 4214784)
  short* YbufT= (short*)(ws + 602112);   // 1204224 shorts -> floats [602112, 1204224) over dead tcat
  short* W1c  = (short*)(ws + 7463680);  // floats [7463680, 7537408) over dead hpart
  short* W2c  = (short*)(ws + 7537408);  // floats [7537408, 7611136)
  float* b1c  = ws + 7611136;            // [7611136, 7611904)
  float* b2c  = ws + 7611904;            // [7611904, 7612672)

  // ---- independent tiny prep ----
  k_tab<<<4,256,0,stream>>>(ctab, stab);
  hipMemcpyAsync(x1, x, (size_t)602112*4, hipMemcpyDeviceToDevice, stream);

  // ---- mamba path ----
  k_ln<<<ROWS,64,0,stream>>>(x, ln1_w, ln1_b, lnb, ROWS);
  k_mgemm<0,1,0,1><<<dim3(24,25,1),256,0,stream>>>(lnb,384,0, in_proj_w,384,0, nullptr,0,0,
                                                   xz,1536,0, ROWS,1536,384, 1.f);
  k_conv<<<(ROWS*DI+255)/256,256,0,stream>>>(xz,conv_w,conv_b,xc,(float4*)dbl);
  k_mgemm<4,0,0,8><<<dim3(3,25,8),256,0,stream>>>(xc,768,0, x_proj_w,768,0, nullptr,0,0,
                                                  dbl,152,0, ROWS,152,768, 1.f);
  // dt_proj: MFMA, single zero-padded k-tile (K=24), softplus+bias epilogue
  k_mgemm<5,0,0,1><<<dim3(12,25,1),256,0,stream>>>(dbl,152,0, dt_proj_w,24,0, dt_proj_b,0,0,
                                                   dtb,768,0, ROWS,768,24, 1.f);
  k_scan1<<<32*192,256,0,stream>>>(dbl,dtb,xc,A_log,hpart,sdt);
  k_scan2<<<(BB*DI)/4,256,0,stream>>>(sdt,A_log,hpart);
  k_scan3<<<32*192,256,0,stream>>>(dbl,dtb,xc,xz,A_log,Dp,hpart,yb);
  k_mgemm<4,0,0,4><<<dim3(6,25,4),256,0,stream>>>(yb,768,0, out_proj_w,768,0, nullptr,0,0,
                                                  x1,384,0, ROWS,384,768, 1.f);

  // ---- einfft path (prep after mamba: overlaid regions now dead) ----
  k_prep<<<(2*784*1568+255)/256,256,0,stream>>>(Wcat,WT,ctab,stab,cw1,cb1,cw2,cb2,W1c,W2c,b1c,b2c,(float4*)Ybuf);
  k_lnT<<<ROWS,64,0,stream>>>(x1, ln2_w, ln2_b, lnT);
  // forward DFT-784: split-K 4, atomic into zeroed Ybuf (A=Wcat bf16, B=lnT bf16)
  k_mgemm<4,1,1,4><<<dim3(6,25,8),256,0,stream>>>(Wcat,784,0, lnT,784,301056, nullptr,0,0,
                                                  Ybuf,384,602112, 1568,384,784, 1.f/56.f);
  // forward DFT-4 along nb -> tcat (bf16)
  k_cfft4<<<(BB*NN*96+255)/256,256,0,stream>>>(Ybuf,tcat);
  // EinFFT layer 1 (relu), A=tcat bf16
  k_mgemm<2,1,1,1><<<dim3(3,25,4),256,0,stream>>>(tcat,768,192, W1c,192,36864, b1c,0,192,
                                                  o1cat,768,192, ROWS,192,192, 1.f);
  // EinFFT layer 2 (soft shrink)
  k_mgemm<3,0,1,1><<<dim3(3,25,4),256,0,stream>>>(o1cat,768,192, W2c,192,36864, b2c,0,192,
                                                  t2cat,768,192, ROWS,192,192, 1.f);
  // inverse DFT-4 -> YbufT[b][c][fcat] (bf16)
  k_cifft4<<<(BB*NN*96+255)/256,256,0,stream>>>(t2cat,YbufT);
  hipMemcpyAsync(d_out, x1, (size_t)602112*4, hipMemcpyDeviceToDevice, stream);
  // inverse DFT-784: split-K 7, atomic into d_out (A=WT bf16, B=YbufT bf16)
  k_mgemm<4,1,1,7><<<dim3(6,13,14),256,0,stream>>>(WT,1568,0, YbufT,1568,602112, nullptr,0,0,
                                                   (float*)d_out,384,301056, 784,384,1568, 1.f/56.f);
}